// Round 1
// baseline (414.854 us; speedup 1.0000x reference)
//
#include <hip/hip_runtime.h>
#include <hip/hip_bf16.h>
#include <stdint.h>

typedef __bf16 bf16_t;
typedef bf16_t bf16x8 __attribute__((ext_vector_type(8)));
typedef float f32x4 __attribute__((ext_vector_type(4)));

#define IN_F 4096
#define OUT_F 4096
#define M_ROWS 8192
#define RANK 16

// ---------------------------------------------------------------------------
// Kernel 1: dequantize 4-bit -> fp32, fold LoRA (Wp = W + B*A), store bf16.
// Wp layout: [OUT_F][IN_F] row-major == B^T layout for the GEMM (K-major).
// Each thread: 8 consecutive weights of one row (4 packed bytes, one scale).
// ---------------------------------------------------------------------------
__global__ __launch_bounds__(256)
void dequant_lora_kernel(const int* __restrict__ qw, const float* __restrict__ wmax,
                         const float* __restrict__ lA, const float* __restrict__ lB,
                         bf16_t* __restrict__ Wp) {
  const int tid = blockIdx.x * 256 + threadIdx.x;   // 2,097,152 threads
  const int f0 = tid * 8;
  const int o  = f0 >> 12;           // row (output feature)
  const int i0 = f0 & (IN_F - 1);    // col (input feature)
  const int4 q4 = *(const int4*)(qw + (f0 >> 1));   // 4 packed bytes (in int32s)
  const float scale = wmax[f0 >> 6];
  const float st = scale * (2.0f / 15.0f);          // table[c]*scale = c*st - scale

  float v[8];
  {
    const int q0 = q4.x, q1 = q4.y, q2 = q4.z, q3 = q4.w;
    v[0] = (float)(q0 & 15)        * st - scale;
    v[1] = (float)((q0 >> 4) & 15) * st - scale;
    v[2] = (float)(q1 & 15)        * st - scale;
    v[3] = (float)((q1 >> 4) & 15) * st - scale;
    v[4] = (float)(q2 & 15)        * st - scale;
    v[5] = (float)((q2 >> 4) & 15) * st - scale;
    v[6] = (float)(q3 & 15)        * st - scale;
    v[7] = (float)((q3 >> 4) & 15) * st - scale;
  }

  // LoRA fold: v[j] += sum_r B[o][r] * A[r][i0+j]
  const float* Brow = lB + o * RANK;
#pragma unroll
  for (int r = 0; r < RANK; ++r) {
    const float br = Brow[r];
    const float4 a0 = *(const float4*)(lA + r * IN_F + i0);
    const float4 a1 = *(const float4*)(lA + r * IN_F + i0 + 4);
    v[0] += br * a0.x; v[1] += br * a0.y; v[2] += br * a0.z; v[3] += br * a0.w;
    v[4] += br * a1.x; v[5] += br * a1.y; v[6] += br * a1.z; v[7] += br * a1.w;
  }

  bf16x8 ov;
#pragma unroll
  for (int j = 0; j < 8; ++j) ov[j] = (bf16_t)v[j];
  *(bf16x8*)(Wp + (size_t)f0) = ov;
}

// ---------------------------------------------------------------------------
// Kernel 2: x fp32 -> bf16 (vectorized)
// ---------------------------------------------------------------------------
__global__ __launch_bounds__(256)
void f32_to_bf16_kernel(const float* __restrict__ x, bf16_t* __restrict__ xb) {
  const size_t tid = (size_t)blockIdx.x * 256 + threadIdx.x;
  const float4 a0 = *(const float4*)(x + tid * 8);
  const float4 a1 = *(const float4*)(x + tid * 8 + 4);
  bf16x8 o;
  o[0] = (bf16_t)a0.x; o[1] = (bf16_t)a0.y; o[2] = (bf16_t)a0.z; o[3] = (bf16_t)a0.w;
  o[4] = (bf16_t)a1.x; o[5] = (bf16_t)a1.y; o[6] = (bf16_t)a1.z; o[7] = (bf16_t)a1.w;
  *(bf16x8*)(xb + tid * 8) = o;
}

// ---------------------------------------------------------------------------
// Kernel 3: C[M][N] = Xb[M][K] * Wp[N][K]^T + bias  (m97-style structure)
// 128x128 tile, BK=32, 256 threads = 4 waves (2x2), 64x64 per wave,
// mfma_f32_16x16x32_bf16, global_load_lds width-16 staging.
// ---------------------------------------------------------------------------
__device__ __forceinline__ void gload16(const void* g, void* l) {
  __builtin_amdgcn_global_load_lds((const __attribute__((address_space(1))) void*)g,
                                   (__attribute__((address_space(3))) void*)l, 16, 0, 0);
}

__global__ __launch_bounds__(256)
void gemm_bt_kernel(const bf16_t* __restrict__ Xb, const bf16_t* __restrict__ Wp,
                    const float* __restrict__ bias, float* __restrict__ C) {
  __shared__ __align__(16) bf16_t As[128][32];
  __shared__ __align__(16) bf16_t Bs[128][32];

  const int bid = blockIdx.x;
  const int bm = bid >> 5;   // 64 m-tiles (consecutive blocks share the X panel)
  const int bn = bid & 31;   // 32 n-tiles

  const int t    = threadIdx.x;
  const int lane = t & 63;
  const int wave = t >> 6;
  const int wr = wave >> 1, wc = wave & 1;
  const int r16 = lane & 15, kg = lane >> 4;

  // staging: issue j covers LDS bytes [(j*256+t)*16, +16) -> row=(idx>>2), col8=(idx&3)*8
  const int srow = t >> 2;
  const int scol = (t & 3) * 8;

  const bf16_t* Ag  = Xb + (size_t)(bm * 128 + srow) * IN_F + scol;
  const bf16_t* Ag2 = Ag + (size_t)64 * IN_F;
  const bf16_t* Bg  = Wp + (size_t)(bn * 128 + srow) * IN_F + scol;
  const bf16_t* Bg2 = Bg + (size_t)64 * IN_F;
  void* la  = &As[srow][scol];
  void* la2 = &As[srow + 64][scol];
  void* lb  = &Bs[srow][scol];
  void* lb2 = &Bs[srow + 64][scol];

  f32x4 acc[4][4] = {};
  const int aoff = wr * 64, boff = wc * 64;

  for (int k0 = 0; k0 < IN_F; k0 += 32) {
    gload16(Ag + k0,  la);
    gload16(Ag2 + k0, la2);
    gload16(Bg + k0,  lb);
    gload16(Bg2 + k0, lb2);
    asm volatile("s_waitcnt vmcnt(0)" ::: "memory");
    __syncthreads();

    bf16x8 af[4], bfr[4];
#pragma unroll
    for (int m = 0; m < 4; ++m)
      af[m] = *(const bf16x8*)&As[aoff + m * 16 + r16][kg * 8];
#pragma unroll
    for (int n = 0; n < 4; ++n)
      bfr[n] = *(const bf16x8*)&Bs[boff + n * 16 + r16][kg * 8];

#pragma unroll
    for (int m = 0; m < 4; ++m)
#pragma unroll
      for (int n = 0; n < 4; ++n)
        acc[m][n] = __builtin_amdgcn_mfma_f32_16x16x32_bf16(af[m], bfr[n], acc[m][n], 0, 0, 0);

    __syncthreads();
  }

  // epilogue: C/D layout col=lane&15, row=(lane>>4)*4+reg  (m89-verified)
#pragma unroll
  for (int n = 0; n < 4; ++n) {
    const int col = bn * 128 + boff + n * 16 + r16;
    const float bv = bias[col];
#pragma unroll
    for (int m = 0; m < 4; ++m) {
      const int grow0 = bm * 128 + aoff + m * 16 + kg * 4;
#pragma unroll
      for (int r = 0; r < 4; ++r)
        C[(size_t)(grow0 + r) * OUT_F + col] = acc[m][n][r] + bv;
    }
  }
}

// ---------------------------------------------------------------------------
extern "C" void kernel_launch(void* const* d_in, const int* in_sizes, int n_in,
                              void* d_out, int out_size, void* d_ws, size_t ws_size,
                              hipStream_t stream) {
  const float* x  = (const float*)d_in[0];
  const int*   qw = (const int*)d_in[1];
  const float* wm = (const float*)d_in[2];
  const float* lA = (const float*)d_in[3];
  const float* lB = (const float*)d_in[4];
  const float* bs = (const float*)d_in[5];
  float* out = (float*)d_out;

  bf16_t* Wp = (bf16_t*)d_ws;                                        // 33.5 MB
  bf16_t* Xb = (bf16_t*)((char*)d_ws + (size_t)OUT_F * IN_F * 2);    // 67 MB

  dequant_lora_kernel<<<OUT_F * IN_F / 8 / 256, 256, 0, stream>>>(qw, wm, lA, lB, Wp);
  f32_to_bf16_kernel<<<M_ROWS * IN_F / 8 / 256, 256, 0, stream>>>(x, Xb);
  gemm_bt_kernel<<<(M_ROWS / 128) * (OUT_F / 128), 256, 0, stream>>>(Xb, Wp, bs, out);
}

// Round 2
// 347.678 us; speedup vs baseline: 1.1932x; 1.1932x over previous
//
#include <hip/hip_runtime.h>
#include <hip/hip_bf16.h>
#include <stdint.h>

typedef __bf16 bf16_t;
typedef bf16_t bf16x8 __attribute__((ext_vector_type(8)));
typedef float f32x4 __attribute__((ext_vector_type(4)));

#define IN_F 4096
#define OUT_F 4096
#define M_ROWS 8192
#define RANK 16

// ---------------------------------------------------------------------------
// Kernel 1: dequantize 4-bit -> fp32, fold LoRA (Wp = W + B*A), store bf16.
// ---------------------------------------------------------------------------
__global__ __launch_bounds__(256)
void dequant_lora_kernel(const int* __restrict__ qw, const float* __restrict__ wmax,
                         const float* __restrict__ lA, const float* __restrict__ lB,
                         bf16_t* __restrict__ Wp) {
  const int tid = blockIdx.x * 256 + threadIdx.x;
  const int f0 = tid * 8;
  const int o  = f0 >> 12;
  const int i0 = f0 & (IN_F - 1);
  const int4 q4 = *(const int4*)(qw + (f0 >> 1));
  const float scale = wmax[f0 >> 6];
  const float st = scale * (2.0f / 15.0f);

  float v[8];
  {
    const int q0 = q4.x, q1 = q4.y, q2 = q4.z, q3 = q4.w;
    v[0] = (float)(q0 & 15)        * st - scale;
    v[1] = (float)((q0 >> 4) & 15) * st - scale;
    v[2] = (float)(q1 & 15)        * st - scale;
    v[3] = (float)((q1 >> 4) & 15) * st - scale;
    v[4] = (float)(q2 & 15)        * st - scale;
    v[5] = (float)((q2 >> 4) & 15) * st - scale;
    v[6] = (float)(q3 & 15)        * st - scale;
    v[7] = (float)((q3 >> 4) & 15) * st - scale;
  }

  const float* Brow = lB + o * RANK;
#pragma unroll
  for (int r = 0; r < RANK; ++r) {
    const float br = Brow[r];
    const float4 a0 = *(const float4*)(lA + r * IN_F + i0);
    const float4 a1 = *(const float4*)(lA + r * IN_F + i0 + 4);
    v[0] += br * a0.x; v[1] += br * a0.y; v[2] += br * a0.z; v[3] += br * a0.w;
    v[4] += br * a1.x; v[5] += br * a1.y; v[6] += br * a1.z; v[7] += br * a1.w;
  }

  bf16x8 ov;
#pragma unroll
  for (int j = 0; j < 8; ++j) ov[j] = (bf16_t)v[j];
  *(bf16x8*)(Wp + (size_t)f0) = ov;
}

// ---------------------------------------------------------------------------
// Kernel 2: x fp32 -> bf16 (vectorized)
// ---------------------------------------------------------------------------
__global__ __launch_bounds__(256)
void f32_to_bf16_kernel(const float* __restrict__ x, bf16_t* __restrict__ xb) {
  const size_t tid = (size_t)blockIdx.x * 256 + threadIdx.x;
  const float4 a0 = *(const float4*)(x + tid * 8);
  const float4 a1 = *(const float4*)(x + tid * 8 + 4);
  bf16x8 o;
  o[0] = (bf16_t)a0.x; o[1] = (bf16_t)a0.y; o[2] = (bf16_t)a0.z; o[3] = (bf16_t)a0.w;
  o[4] = (bf16_t)a1.x; o[5] = (bf16_t)a1.y; o[6] = (bf16_t)a1.z; o[7] = (bf16_t)a1.w;
  *(bf16x8*)(xb + tid * 8) = o;
}

// ---------------------------------------------------------------------------
// Kernel 3: 256x256-tile 8-phase GEMM.  C[M][N] = Xb[M][K] * Wp[N][K]^T + bias
// 512 thr = 8 waves (2M x 4N), per-wave 128x64, BK=64, double-buffered LDS,
// st-style XOR swizzle (both sides), counted vmcnt(4), setprio around MFMA.
// ---------------------------------------------------------------------------
__device__ __forceinline__ void gld(const bf16_t* src, char* dst) {
  __builtin_amdgcn_global_load_lds((const __attribute__((address_space(1))) void*)src,
                                   (__attribute__((address_space(3))) void*)dst, 16, 0, 0);
}

#define BARRIER() __builtin_amdgcn_s_barrier()
#define WAIT_LGKM0() do { asm volatile("s_waitcnt lgkmcnt(0)" ::: "memory"); \
                          __builtin_amdgcn_sched_barrier(0); } while (0)
#define WAIT_VM(n) asm volatile("s_waitcnt vmcnt(" #n ")" ::: "memory")

// LDS fragment reads (byte addressing; cb is the pre-swizzled column byte)
#define LDA(buf, m, cb) (*(const bf16x8*)(ldsA + ((buf)*32768 + aRowB + (m)*2048 + (cb))))
#define LDB(buf, n, cb) (*(const bf16x8*)(ldsB + ((buf)*32768 + bRowB + (n)*2048 + (cb))))

// staging: one gload covers 64 rows x 64 cols bf16 (8 KiB); linear LDS dest,
// pre-swizzled global source column (sc).
#define STAGE_A(kt, buf) do { \
  _Pragma("unroll") for (int g = 0; g < 4; ++g) \
    gld(Asrc + ((size_t)g*64*IN_F + (size_t)(kt)*64), ldsA + ((buf)*32768 + g*8192 + tid*16)); \
} while (0)
#define STAGE_B_HALF(kt, buf, h) do { \
  _Pragma("unroll") for (int g = 0; g < 2; ++g) \
    gld(Bsrc + ((size_t)((h)*2+g)*64*IN_F + (size_t)(kt)*64), \
        ldsB + ((buf)*32768 + ((h)*2+g)*8192 + tid*16)); \
} while (0)
#define STAGE_B(kt, buf) do { STAGE_B_HALF(kt, buf, 0); STAGE_B_HALF(kt, buf, 1); } while (0)

#define READ_B_ALL(buf) do { \
  _Pragma("unroll") for (int n = 0; n < 4; ++n) { \
    b[n][0] = LDB(buf, n, cA0); b[n][1] = LDB(buf, n, cA1); } \
} while (0)

#define PHASE(Q, EXTRA, STAGE, TAILWAIT) do { \
  a[0][0] = LDA(cur, 2*(Q),   cA0); a[0][1] = LDA(cur, 2*(Q),   cA1); \
  a[1][0] = LDA(cur, 2*(Q)+1, cA0); a[1][1] = LDA(cur, 2*(Q)+1, cA1); \
  EXTRA; STAGE; \
  BARRIER(); \
  WAIT_LGKM0(); \
  __builtin_amdgcn_s_setprio(1); \
  _Pragma("unroll") for (int kh = 0; kh < 2; ++kh) \
    _Pragma("unroll") for (int mm = 0; mm < 2; ++mm) \
      _Pragma("unroll") for (int n = 0; n < 4; ++n) \
        acc[2*(Q)+mm][n] = __builtin_amdgcn_mfma_f32_16x16x32_bf16( \
            a[mm][kh], b[n][kh], acc[2*(Q)+mm][n], 0, 0, 0); \
  __builtin_amdgcn_s_setprio(0); \
  TAILWAIT; \
  BARRIER(); \
} while (0)

__global__ __launch_bounds__(512, 2)
void gemm_8phase_kernel(const bf16_t* __restrict__ Xb, const bf16_t* __restrict__ Wp,
                        const float* __restrict__ bias, float* __restrict__ C) {
  __shared__ __align__(16) bf16_t As[2][256][64];   // 64 KiB
  __shared__ __align__(16) bf16_t Bs[2][256][64];   // 64 KiB
  char* ldsA = (char*)As;
  char* ldsB = (char*)Bs;

  const int tid  = threadIdx.x;
  const int lane = tid & 63;
  const int wave = tid >> 6;
  const int wr = wave >> 2;           // 0..1 -> M half
  const int wc = wave & 3;            // 0..3 -> N quarter
  const int r16 = lane & 15;
  const int kg  = lane >> 4;          // 0..3

  const int bid = blockIdx.x;
  const int bm = bid >> 4;            // 0..31
  const int bn = bid & 15;            // 0..15

  // staging per-thread: row-in-64-group + pre-swizzled source column
  const int sr = tid >> 3;                          // 0..63
  const int sc = ((tid & 7) ^ (sr & 7)) << 3;       // element col (swizzled)
  const bf16_t* Asrc = Xb + (size_t)(bm * 256 + sr) * IN_F + sc;
  const bf16_t* Bsrc = Wp + (size_t)(bn * 256 + sr) * IN_F + sc;

  // read-side per-thread offsets
  const int aRowB = (wr * 128 + r16) * 128;         // byte row offset in A tile
  const int bRowB = (wc * 64 + r16) * 128;          // byte row offset in B tile
  const int cA0 = (kg * 16) ^ ((r16 & 7) << 4);     // swizzled col byte, k-half 0
  const int cA1 = cA0 ^ 64;                         // k-half 1

  f32x4 acc[8][4] = {};
  bf16x8 a[2][2], b[4][2];

  // prologue: stage K-tiles 0 and 1
  STAGE_A(0, 0); STAGE_B(0, 0);
  STAGE_A(1, 1); STAGE_B(1, 1);
  WAIT_VM(8);            // tile 0 landed; tile 1's 8 loads still in flight
  BARRIER();

  for (int t = 0; t < 64; ++t) {
    const int cur = t & 1;
    PHASE(0, READ_B_ALL(cur),
          { if (t >= 1 && t < 63) STAGE_A(t + 1, cur ^ 1); }, {});
    PHASE(1, {},
          { if (t < 62) STAGE_B_HALF(t + 2, cur, 0); }, {});
    PHASE(2, {},
          { if (t < 62) STAGE_B_HALF(t + 2, cur, 1); }, {});
    PHASE(3, {}, {},
          { if (t < 62) { WAIT_VM(4); } else if (t == 62) { WAIT_VM(0); } });
  }

  // epilogue: C/D layout col=lane&15, row=kg*4+reg (m89-verified)
#pragma unroll
  for (int n = 0; n < 4; ++n) {
    const int col = bn * 256 + wc * 64 + n * 16 + r16;
    const float bv = bias[col];
#pragma unroll
    for (int m = 0; m < 8; ++m) {
      const int row0 = bm * 256 + wr * 128 + m * 16 + kg * 4;
#pragma unroll
      for (int r = 0; r < 4; ++r)
        C[(size_t)(row0 + r) * OUT_F + col] = acc[m][n][r] + bv;
    }
  }
}

// ---------------------------------------------------------------------------
extern "C" void kernel_launch(void* const* d_in, const int* in_sizes, int n_in,
                              void* d_out, int out_size, void* d_ws, size_t ws_size,
                              hipStream_t stream) {
  const float* x  = (const float*)d_in[0];
  const int*   qw = (const int*)d_in[1];
  const float* wm = (const float*)d_in[2];
  const float* lA = (const float*)d_in[3];
  const float* lB = (const float*)d_in[4];
  const float* bs = (const float*)d_in[5];
  float* out = (float*)d_out;

  bf16_t* Wp = (bf16_t*)d_ws;                                        // 33.5 MB
  bf16_t* Xb = (bf16_t*)((char*)d_ws + (size_t)OUT_F * IN_F * 2);    // 67 MB

  dequant_lora_kernel<<<OUT_F * IN_F / 8 / 256, 256, 0, stream>>>(qw, wm, lA, lB, Wp);
  f32_to_bf16_kernel<<<M_ROWS * IN_F / 8 / 256, 256, 0, stream>>>(x, Xb);
  gemm_8phase_kernel<<<(M_ROWS / 256) * (OUT_F / 256), 512, 0, stream>>>(Xb, Wp, bs, out);
}